// Round 2
// baseline (188.886 us; speedup 1.0000x reference)
//
#include <hip/hip_runtime.h>

#define BLOCK 256

// ---- cross-lane xor-shuffle within 16-lane rows ----
template<int CTRL>
__device__ __forceinline__ float dpp_f(float v) {
  return __int_as_float(__builtin_amdgcn_mov_dpp(__float_as_int(v), CTRL, 0xF, 0xF, true));
}

template<int MASK>
__device__ __forceinline__ float shx(float v) {
  if constexpr (MASK == 1)      return dpp_f<0xB1>(v);   // quad_perm [1,0,3,2]
  else if constexpr (MASK == 2) return dpp_f<0x4E>(v);   // quad_perm [2,3,0,1]
  else if constexpr (MASK == 8) return dpp_f<0x128>(v);  // row_ror:8 == xor 8 in row16
  else  // MASK == 4: ds_swizzle BitMode xor=4 (LDS pipe — deliberate offload from VALU)
    return __int_as_float(__builtin_amdgcn_ds_swizzle(__float_as_int(v), 0x101F));
}

// ---- gate helpers ----
template<int MASK>
__device__ __forceinline__ void rx_cross(float (&are)[16], float (&aim)[16], float c, float s) {
#pragma unroll
  for (int r = 0; r < 16; ++r) {
    float pre = shx<MASK>(are[r]);
    float pim = shx<MASK>(aim[r]);
    float nre = __builtin_fmaf(c, are[r],  s * pim);
    float nim = __builtin_fmaf(c, aim[r], -s * pre);
    are[r] = nre; aim[r] = nim;
  }
}

template<int RM>
__device__ __forceinline__ void rx_local(float (&are)[16], float (&aim)[16], float c, float s) {
#pragma unroll
  for (int r = 0; r < 16; ++r) {
    if (!(r & RM)) {
      const int r1 = r | RM;
      float a0re = are[r],  a0im = aim[r];
      float a1re = are[r1], a1im = aim[r1];
      are[r]  = __builtin_fmaf(c, a0re,  s * a1im);
      aim[r]  = __builtin_fmaf(c, a0im, -s * a1re);
      are[r1] = __builtin_fmaf(c, a1re,  s * a0im);
      aim[r1] = __builtin_fmaf(c, a1im, -s * a0re);
    }
  }
}

template<int MASK>
__device__ __forceinline__ void cnot_cross(float (&are)[16], float (&aim)[16], bool ctrl) {
#pragma unroll
  for (int r = 0; r < 16; ++r) {
    float pre = shx<MASK>(are[r]);
    float pim = shx<MASK>(aim[r]);
    are[r] = ctrl ? pre : are[r];
    aim[r] = ctrl ? pim : aim[r];
  }
}

__device__ __forceinline__ void swap_f(float& a, float& b) { float t = a; a = b; b = t; }

__global__ __launch_bounds__(BLOCK) void qcnn_kernel(
    const float* __restrict__ x,   const float* __restrict__ fcw,
    const float* __restrict__ fcb, const float* __restrict__ qp,
    const float* __restrict__ pw,  const float* __restrict__ pb,
    float* __restrict__ out)
{
  const int tid  = threadIdx.x;
  const int wave = tid >> 6;
  const int lane = tid & 63;
  const int u = lane & 15;        // sub-lane within sample (amp bits 7..4)
  const int g = lane >> 4;        // sample-in-wave
  const int smp = (blockIdx.x * (BLOCK / 64) + wave) * 4 + g;

  // ---- Phase A: half-angles h_q = 0.5*(x . fc_w[q] + fc_b[q]); weights via L1 ----
  const float* xrow = x + (size_t)smp * 512;
  float acc[8];
#pragma unroll
  for (int q = 0; q < 8; ++q) acc[q] = 0.f;
#pragma unroll
  for (int t = 0; t < 8; ++t) {
    const float4 xv = *(const float4*)(xrow + u * 4 + t * 64);
#pragma unroll
    for (int q = 0; q < 8; ++q) {
      const float4 wv = *(const float4*)(fcw + q * 512 + u * 4 + t * 64);
      acc[q] = __builtin_fmaf(xv.x, wv.x, acc[q]);
      acc[q] = __builtin_fmaf(xv.y, wv.y, acc[q]);
      acc[q] = __builtin_fmaf(xv.z, wv.z, acc[q]);
      acc[q] = __builtin_fmaf(xv.w, wv.w, acc[q]);
    }
  }
#pragma unroll
  for (int q = 0; q < 8; ++q) {
    float a = acc[q];
    a += shx<1>(a); a += shx<2>(a); a += shx<4>(a); a += shx<8>(a);
    acc[q] = 0.5f * (a + fcb[q]);       // half-angle
  }
  float cs[8], sn[8];
#pragma unroll
  for (int q = 0; q < 8; ++q) { cs[q] = __cosf(acc[q]); sn[q] = __sinf(acc[q]); }

  // ---- Phase B: product state WITH layer-0 RX folded in ----
  // per-qubit state after RY(th)+RX(phi): bit0 -> (cf*c, -sf*s), bit1 -> (cf*s, -sf*c)
  float p45r[4], p45i[4], p67r[4], p67i[4];
  {
    float Ar[4], Ai[4], Cr[4], Ci[4];   // qubits 4..7: v0=(Ar,Ai), v1=(Cr,Ci)
#pragma unroll
    for (int j = 0; j < 4; ++j) {
      const int q = 4 + j;
      const float cf = __cosf(0.5f * qp[q]);
      const float sf = __sinf(0.5f * qp[q]);
      Ar[j] = cf * cs[q]; Ai[j] = -sf * sn[q];
      Cr[j] = cf * sn[q]; Ci[j] = -sf * cs[q];
    }
    // p45[i] = state(q4, i>>1) (x) state(q5, i&1); p67[i] = state(q6, i>>1) (x) state(q7, i&1)
#pragma unroll
    for (int i = 0; i < 4; ++i) {
      const float ar = (i & 2) ? Cr[0] : Ar[0], ai = (i & 2) ? Ci[0] : Ai[0];
      const float br = (i & 1) ? Cr[1] : Ar[1], bi = (i & 1) ? Ci[1] : Ai[1];
      p45r[i] = __builtin_fmaf(ar, br, -ai * bi);
      p45i[i] = __builtin_fmaf(ar, bi,  ai * br);
      const float er = (i & 2) ? Cr[2] : Ar[2], ei = (i & 2) ? Ci[2] : Ai[2];
      const float fr = (i & 1) ? Cr[3] : Ar[3], fi = (i & 1) ? Ci[3] : Ai[3];
      p67r[i] = __builtin_fmaf(er, fr, -ei * fi);
      p67i[i] = __builtin_fmaf(er, fi,  ei * fr);
    }
  }
  float Lre, Lim;
  {
    // qubits 0..3 on lane bits u3..u0 (qubit q <-> bit (8>>q))
    const float cf0 = __cosf(0.5f * qp[0]), sf0 = __sinf(0.5f * qp[0]);
    const bool b0 = (u & 8) != 0;
    float ar =  cf0 * (b0 ? sn[0] : cs[0]);
    float ai = -sf0 * (b0 ? cs[0] : sn[0]);
#pragma unroll
    for (int q = 1; q < 4; ++q) {
      const float cf = __cosf(0.5f * qp[q]), sf = __sinf(0.5f * qp[q]);
      const bool b = (u & (8 >> q)) != 0;
      const float br =  cf * (b ? sn[q] : cs[q]);
      const float bi = -sf * (b ? cs[q] : sn[q]);
      const float nr = __builtin_fmaf(ar, br, -ai * bi);
      const float ni = __builtin_fmaf(ar, bi,  ai * br);
      ar = nr; ai = ni;
    }
    Lre = ar; Lim = ai;
  }
  float are[16], aim[16];
#pragma unroll
  for (int r = 0; r < 16; ++r) {
    const float fr = __builtin_fmaf(p45r[r >> 2], p67r[r & 3], -p45i[r >> 2] * p67i[r & 3]);
    const float fi = __builtin_fmaf(p45r[r >> 2], p67i[r & 3],  p45i[r >> 2] * p67r[r & 3]);
    are[r] = __builtin_fmaf(Lre, fr, -Lim * fi);
    aim[r] = __builtin_fmaf(Lre, fi,  Lim * fr);
  }

  // ---- Phase C: rings (layer 0 RX already folded), RX for layers 1,2 ----
  const bool cn01 = (u & 8) != 0;
  const bool cn12 = (u & 4) != 0;
  const bool cn23 = (u & 2) != 0;
  const bool cn34 = (u & 1) != 0;
#pragma unroll
  for (int l = 0; l < 3; ++l) {
    if (l > 0) {
      float gc[8], gs[8];
#pragma unroll
      for (int q = 0; q < 8; ++q) {
        gc[q] = __cosf(0.5f * qp[l * 8 + q]);
        gs[q] = __sinf(0.5f * qp[l * 8 + q]);
      }
      rx_cross<8>(are, aim, gc[0], gs[0]);   // qubit0 (u3)
      rx_cross<4>(are, aim, gc[1], gs[1]);   // qubit1 (u2)
      rx_cross<2>(are, aim, gc[2], gs[2]);   // qubit2 (u1)
      rx_cross<1>(are, aim, gc[3], gs[3]);   // qubit3 (u0)
      rx_local<8>(are, aim, gc[4], gs[4]);   // qubit4 (r3)
      rx_local<4>(are, aim, gc[5], gs[5]);   // qubit5 (r2)
      rx_local<2>(are, aim, gc[6], gs[6]);   // qubit6 (r1)
      rx_local<1>(are, aim, gc[7], gs[7]);   // qubit7 (r0)
    }
    // CNOT ring, exact order
    cnot_cross<4>(are, aim, cn01);           // (0,1): tgt u2
    cnot_cross<2>(are, aim, cn12);           // (1,2): tgt u1
    cnot_cross<1>(are, aim, cn23);           // (2,3): tgt u0
    // (3,4): ctrl u0, tgt r3 -> conditional in-register swap r <-> r+8
#pragma unroll
    for (int r = 0; r < 8; ++r) {
      float t0 = cn34 ? are[r + 8] : are[r];
      float t1 = cn34 ? are[r]     : are[r + 8];
      are[r] = t0; are[r + 8] = t1;
      float t2 = cn34 ? aim[r + 8] : aim[r];
      float t3 = cn34 ? aim[r]     : aim[r + 8];
      aim[r] = t2; aim[r + 8] = t3;
    }
    // (4,5): ctrl r3, tgt r2 -> static rename (free)
    swap_f(are[8], are[12]);  swap_f(are[9], are[13]);  swap_f(are[10], are[14]); swap_f(are[11], are[15]);
    swap_f(aim[8], aim[12]);  swap_f(aim[9], aim[13]);  swap_f(aim[10], aim[14]); swap_f(aim[11], aim[15]);
    // (5,6): ctrl r2, tgt r1
    swap_f(are[4], are[6]);   swap_f(are[5], are[7]);   swap_f(are[12], are[14]); swap_f(are[13], are[15]);
    swap_f(aim[4], aim[6]);   swap_f(aim[5], aim[7]);   swap_f(aim[12], aim[14]); swap_f(aim[13], aim[15]);
    // (6,7): ctrl r1, tgt r0
    swap_f(are[2], are[3]);   swap_f(are[6], are[7]);   swap_f(are[10], are[11]); swap_f(are[14], are[15]);
    swap_f(aim[2], aim[3]);   swap_f(aim[6], aim[7]);   swap_f(aim[10], aim[11]); swap_f(aim[14], aim[15]);
    // (7,0): ctrl r0 (odd regs), tgt qubit0 = u3 -> unconditional xor-8 permute of odd regs
#pragma unroll
    for (int r = 1; r < 16; r += 2) {
      are[r] = shx<8>(are[r]);
      aim[r] = shx<8>(aim[r]);
    }
  }

  // ---- Phase D: measure <Z_q> ----
  float p[16];
#pragma unroll
  for (int r = 0; r < 16; ++r) p[r] = are[r] * are[r] + aim[r] * aim[r];
  float e0[8], d7 = 0.f;
#pragma unroll
  for (int k = 0; k < 8; ++k) { e0[k] = p[2*k] + p[2*k+1]; d7 += p[2*k] - p[2*k+1]; }
  float e1[4], d6 = 0.f;
#pragma unroll
  for (int k = 0; k < 4; ++k) { e1[k] = e0[2*k] + e0[2*k+1]; d6 += e0[2*k] - e0[2*k+1]; }
  float e2[2], d5 = 0.f;
#pragma unroll
  for (int k = 0; k < 2; ++k) { e2[k] = e1[2*k] + e1[2*k+1]; d5 += e1[2*k] - e1[2*k+1]; }
  float S  = e2[0] + e2[1];
  float d4 = e2[0] - e2[1];

  float t;
  t = shx<1>(S);  float d3 = S - t;  S += t;
  d4 += shx<1>(d4); d5 += shx<1>(d5); d6 += shx<1>(d6); d7 += shx<1>(d7);
  t = shx<2>(S);  float d2 = S - t;  S += t;
  d3 += shx<2>(d3); d4 += shx<2>(d4); d5 += shx<2>(d5); d6 += shx<2>(d6); d7 += shx<2>(d7);
  t = shx<4>(S);  float d1 = S - t;  S += t;
  d2 += shx<4>(d2); d3 += shx<4>(d3); d4 += shx<4>(d4); d5 += shx<4>(d5); d6 += shx<4>(d6); d7 += shx<4>(d7);
  t = shx<8>(S);  float d0 = S - t;  S += t;
  d1 += shx<8>(d1); d2 += shx<8>(d2); d3 += shx<8>(d3); d4 += shx<8>(d4); d5 += shx<8>(d5); d6 += shx<8>(d6); d7 += shx<8>(d7);

  float z[8];
  z[0] = (u & 8) ? -d0 : d0;
  z[1] = (u & 4) ? -d1 : d1;
  z[2] = (u & 2) ? -d2 : d2;
  z[3] = (u & 1) ? -d3 : d3;
  z[4] = d4; z[5] = d5; z[6] = d6; z[7] = d7;

  // ---- Phase E: out = z @ post_w^T + post_b; pw rows (o*8..o*8+7) via L1 ----
  float* orow = out + (size_t)smp * 512;
#pragma unroll
  for (int tt = 0; tt < 8; ++tt) {
    const int o = u * 4 + tt * 64;
    const float4 pbv = *(const float4*)(pb + o);
    float4 r4;
    float* comp[4] = { &r4.x, &r4.y, &r4.z, &r4.w };
    const float pbc[4] = { pbv.x, pbv.y, pbv.z, pbv.w };
#pragma unroll
    for (int k = 0; k < 4; ++k) {
      const float4 wlo = *(const float4*)(pw + (size_t)(o + k) * 8);
      const float4 whi = *(const float4*)(pw + (size_t)(o + k) * 8 + 4);
      float v = pbc[k];
      v = __builtin_fmaf(z[0], wlo.x, v);
      v = __builtin_fmaf(z[1], wlo.y, v);
      v = __builtin_fmaf(z[2], wlo.z, v);
      v = __builtin_fmaf(z[3], wlo.w, v);
      v = __builtin_fmaf(z[4], whi.x, v);
      v = __builtin_fmaf(z[5], whi.y, v);
      v = __builtin_fmaf(z[6], whi.z, v);
      v = __builtin_fmaf(z[7], whi.w, v);
      *comp[k] = v;
    }
    *(float4*)(orow + o) = r4;
  }
}

extern "C" void kernel_launch(void* const* d_in, const int* in_sizes, int n_in,
                              void* d_out, int out_size, void* d_ws, size_t ws_size,
                              hipStream_t stream) {
  const float* x   = (const float*)d_in[0];
  const float* fcw = (const float*)d_in[1];
  const float* fcb = (const float*)d_in[2];
  const float* qp  = (const float*)d_in[3];
  const float* pw  = (const float*)d_in[4];
  const float* pb  = (const float*)d_in[5];
  float* out = (float*)d_out;

  // 32768 samples / (4 per wave * 4 waves per block) = 2048 blocks
  dim3 grid(2048), block(BLOCK);
  hipLaunchKernelGGL(qcnn_kernel, grid, block, 0, stream, x, fcw, fcb, qp, pw, pb, out);
}

// Round 3
// 139.815 us; speedup vs baseline: 1.3510x; 1.3510x over previous
//
#include <hip/hip_runtime.h>

#define BLOCK 512
typedef float v2f __attribute__((ext_vector_type(2)));

// ---------- packed fp32 (VOP3P) ----------
// d = a*b + c, componentwise
__device__ __forceinline__ v2f pk_fma(v2f a, v2f b, v2f c) {
  v2f d;
  asm("v_pk_fma_f32 %0, %1, %2, %3" : "=v"(d) : "v"(a), "v"(b), "v"(c));
  return d;
}
// d = (s.lo * p.hi, s.hi * p.lo)   -- component-swapped src1 via op_sel
__device__ __forceinline__ v2f pk_mul_swap(v2f s, v2f p) {
  v2f d;
  asm("v_pk_mul_f32 %0, %1, %2 op_sel:[0,1] op_sel_hi:[1,0]" : "=v"(d) : "v"(s), "v"(p));
  return d;
}

// ---------- cross-lane xor within 16-lane rows ----------
template<int CTRL>
__device__ __forceinline__ float dpp_f(float v) {
  return __int_as_float(__builtin_amdgcn_mov_dpp(__float_as_int(v), CTRL, 0xF, 0xF, true));
}
template<int MASK>
__device__ __forceinline__ float shx(float v) {
  if constexpr (MASK == 1)      return dpp_f<0xB1>(v);   // quad_perm xor1
  else if constexpr (MASK == 2) return dpp_f<0x4E>(v);   // quad_perm xor2
  else if constexpr (MASK == 8) return dpp_f<0x128>(v);  // row_ror:8 == xor8 in row16
  else  // MASK == 4: ds_swizzle BitMode xor=4
    return __int_as_float(__builtin_amdgcn_ds_swizzle(__float_as_int(v), 0x101F));
}

// conditional CNOT as a single bank-masked DPP per component:
// lanes in enabled banks take partner value, others keep their own.
template<int CTRL, int BANK>
__device__ __forceinline__ void cnot_dpp(v2f& a) {
  a.x = __int_as_float(__builtin_amdgcn_update_dpp(
      __float_as_int(a.x), __float_as_int(a.x), CTRL, 0xF, BANK, false));
  a.y = __int_as_float(__builtin_amdgcn_update_dpp(
      __float_as_int(a.y), __float_as_int(a.y), CTRL, 0xF, BANK, false));
}

__device__ __forceinline__ v2f cmul(v2f A, v2f B) {
  v2f d;
  d.x = __builtin_fmaf(A.x, B.x, -(A.y * B.y));
  d.y = __builtin_fmaf(A.x, B.y,  (A.y * B.x));
  return d;
}
__device__ __forceinline__ void swap_v(v2f& a, v2f& b) { v2f t = a; a = b; b = t; }

// qubit->bit mapping: q0->u8, q1->u2, q2->u4, q3->u1, q4->r8, q5->r4, q6->r2, q7->r1
__global__ __launch_bounds__(BLOCK, 8) void qcnn_kernel(
    const float* __restrict__ x,   const float* __restrict__ fcw,
    const float* __restrict__ fcb, const float* __restrict__ qp,
    const float* __restrict__ pw,  const float* __restrict__ pb,
    float* __restrict__ out)
{
  __shared__ float s_fcw[8 * 512];   // [q][e]
  __shared__ float s_pwt[8 * 512];   // transposed [q][o]
  __shared__ float s_pb[512];
  __shared__ v2f   s_trig[3][8];     // (cos, sin) of 0.5*qp

  const int tid = threadIdx.x;

  // ---- stage weights into LDS (wave-uniform broadcast reads later) ----
#pragma unroll
  for (int i = tid; i < 1024; i += BLOCK)
    ((float4*)s_fcw)[i] = ((const float4*)fcw)[i];
#pragma unroll
  for (int i = tid; i < 4096; i += BLOCK)
    s_pwt[i] = pw[(i & 511) * 8 + (i >> 9)];
  if (tid < 128) ((float4*)s_pb)[tid] = ((const float4*)pb)[tid];
  if (tid < 24) {
    const float h = 0.5f * qp[tid];
    v2f cspair; cspair.x = __cosf(h); cspair.y = __sinf(h);
    s_trig[tid >> 3][tid & 7] = cspair;
  }
  __syncthreads();

  const int wave = tid >> 6;
  const int lane = tid & 63;
  const int u = lane & 15;
  const int g = lane >> 4;
  const int smp = (blockIdx.x * (BLOCK / 64) + wave) * 4 + g;

  // ---- Phase A: angles via packed dot products ----
  const float* xrow = x + (size_t)smp * 512;
  v2f acc2[8];
#pragma unroll
  for (int q = 0; q < 8; ++q) { acc2[q].x = 0.f; acc2[q].y = 0.f; }
#pragma unroll
  for (int t = 0; t < 8; ++t) {
    const float4 xv = *(const float4*)(xrow + u * 4 + t * 64);
    v2f x01; x01.x = xv.x; x01.y = xv.y;
    v2f x23; x23.x = xv.z; x23.y = xv.w;
#pragma unroll
    for (int q = 0; q < 8; ++q) {
      const float4 wv = *(const float4*)(s_fcw + q * 512 + u * 4 + t * 64);
      v2f w01; w01.x = wv.x; w01.y = wv.y;
      v2f w23; w23.x = wv.z; w23.y = wv.w;
      acc2[q] = pk_fma(x01, w01, acc2[q]);
      acc2[q] = pk_fma(x23, w23, acc2[q]);
    }
  }
  float cs[8], sn[8];
#pragma unroll
  for (int q = 0; q < 8; ++q) {
    float a_ = acc2[q].x + acc2[q].y;
    a_ += shx<1>(a_); a_ += shx<2>(a_); a_ += shx<4>(a_); a_ += shx<8>(a_);
    const float h = 0.5f * (a_ + fcb[q]);   // half-angle
    cs[q] = __cosf(h);
    sn[q] = __sinf(h);
  }

  // ---- Phase B: product state with layer-0 RX folded ----
  // single-qubit post-RY+RX state: bit0 -> (cf*c, -sf*s), bit1 -> (cf*s, -sf*c)
  v2f L;
  {
    v2f t0 = s_trig[0][0];
    const bool b0 = (u & 8) != 0;
    L.x =  t0.x * (b0 ? sn[0] : cs[0]);
    L.y = -t0.y * (b0 ? cs[0] : sn[0]);
    const int bits[3] = {2, 4, 1};   // qubit1->u2, qubit2->u4, qubit3->u1
#pragma unroll
    for (int q = 1; q < 4; ++q) {
      v2f tq = s_trig[0][q];
      const bool b = (u & bits[q - 1]) != 0;
      v2f v;
      v.x =  tq.x * (b ? sn[q] : cs[q]);
      v.y = -tq.y * (b ? cs[q] : sn[q]);
      L = cmul(L, v);
    }
  }
  v2f A4[4], C4[4];
#pragma unroll
  for (int j = 0; j < 4; ++j) {
    const int q = 4 + j;
    v2f tq = s_trig[0][q];
    A4[j].x =  tq.x * cs[q];  A4[j].y = -tq.y * sn[q];
    C4[j].x =  tq.x * sn[q];  C4[j].y = -tq.y * cs[q];
  }
  v2f p45[4], p67[4];
#pragma unroll
  for (int i = 0; i < 4; ++i) {
    p45[i] = cmul((i & 2) ? C4[0] : A4[0], (i & 1) ? C4[1] : A4[1]);
    p67[i] = cmul((i & 2) ? C4[2] : A4[2], (i & 1) ? C4[3] : A4[3]);
  }
  v2f Lp[4];
#pragma unroll
  for (int i = 0; i < 4; ++i) Lp[i] = cmul(L, p45[i]);
  v2f a[16];
#pragma unroll
  for (int r = 0; r < 16; ++r) a[r] = cmul(Lp[r >> 2], p67[r & 3]);

  // ---- Phase C: layers (RX skipped for l=0, folded above) ----
  const bool cn12 = (u & 2) != 0;   // CNOT(1,2) ctrl = qubit1 = u2-bit... (u&2)
  const bool cn34 = (u & 1) != 0;   // CNOT(3,4) ctrl = qubit3 = u1-bit (u&1)
#pragma unroll
  for (int l = 0; l < 3; ++l) {
    if (l > 0) {
      // RX qubit0 (cross xor8)
      {
        v2f tq = s_trig[l][0];
        const float c = tq.x;
        v2f ss; ss.x = tq.y; ss.y = -tq.y;
        v2f cc; cc.x = c; cc.y = c;
#pragma unroll
        for (int r = 0; r < 16; ++r) {
          v2f psw;  // (im_partner, re_partner)
          psw.x = shx<8>(a[r].y);
          psw.y = shx<8>(a[r].x);
          v2f t; asm("v_pk_mul_f32 %0, %1, %2" : "=v"(t) : "v"(ss), "v"(psw));
          a[r] = pk_fma(cc, a[r], t);
        }
      }
      // RX qubit1 (cross xor2)
      {
        v2f tq = s_trig[l][1];
        v2f ss; ss.x = tq.y; ss.y = -tq.y;
        v2f cc; cc.x = tq.x; cc.y = tq.x;
#pragma unroll
        for (int r = 0; r < 16; ++r) {
          v2f psw; psw.x = shx<2>(a[r].y); psw.y = shx<2>(a[r].x);
          v2f t; asm("v_pk_mul_f32 %0, %1, %2" : "=v"(t) : "v"(ss), "v"(psw));
          a[r] = pk_fma(cc, a[r], t);
        }
      }
      // RX qubit2 (cross xor4, LDS swizzle)
      {
        v2f tq = s_trig[l][2];
        v2f ss; ss.x = tq.y; ss.y = -tq.y;
        v2f cc; cc.x = tq.x; cc.y = tq.x;
#pragma unroll
        for (int r = 0; r < 16; ++r) {
          v2f psw; psw.x = shx<4>(a[r].y); psw.y = shx<4>(a[r].x);
          v2f t; asm("v_pk_mul_f32 %0, %1, %2" : "=v"(t) : "v"(ss), "v"(psw));
          a[r] = pk_fma(cc, a[r], t);
        }
      }
      // RX qubit3 (cross xor1)
      {
        v2f tq = s_trig[l][3];
        v2f ss; ss.x = tq.y; ss.y = -tq.y;
        v2f cc; cc.x = tq.x; cc.y = tq.x;
#pragma unroll
        for (int r = 0; r < 16; ++r) {
          v2f psw; psw.x = shx<1>(a[r].y); psw.y = shx<1>(a[r].x);
          v2f t; asm("v_pk_mul_f32 %0, %1, %2" : "=v"(t) : "v"(ss), "v"(psw));
          a[r] = pk_fma(cc, a[r], t);
        }
      }
      // RX qubits 4..7 (local register pairs)
      {
        const int RM[4] = {8, 4, 2, 1};
#pragma unroll
        for (int j = 0; j < 4; ++j) {
          v2f tq = s_trig[l][4 + j];
          v2f ss; ss.x = tq.y; ss.y = -tq.y;
          v2f cc; cc.x = tq.x; cc.y = tq.x;
#pragma unroll
          for (int r = 0; r < 16; ++r) {
            if (!(r & RM[j])) {
              const int r1 = r | RM[j];
              v2f tlo = pk_mul_swap(ss, a[r1]);   // (s*im1, -s*re1)
              v2f thi = pk_mul_swap(ss, a[r]);
              a[r]  = pk_fma(cc, a[r],  tlo);
              a[r1] = pk_fma(cc, a[r1], thi);
            }
          }
        }
      }
    }
    // CNOT(0,1): ctrl u&8 (banks 2,3), tgt qubit1=xor2 -> masked DPP
#pragma unroll
    for (int r = 0; r < 16; ++r) cnot_dpp<0x4E, 0xC>(a[r]);
    // CNOT(1,2): ctrl u&2, tgt qubit2=xor4 -> swizzle + cndmask
#pragma unroll
    for (int r = 0; r < 16; ++r) {
      const float sx = shx<4>(a[r].x);
      const float sy = shx<4>(a[r].y);
      a[r].x = cn12 ? sx : a[r].x;
      a[r].y = cn12 ? sy : a[r].y;
    }
    // CNOT(2,3): ctrl u&4 (banks 1,3), tgt qubit3=xor1 -> masked DPP
#pragma unroll
    for (int r = 0; r < 16; ++r) cnot_dpp<0xB1, 0xA>(a[r]);
    // CNOT(3,4): ctrl u&1, tgt r-bit8 -> conditional swap
#pragma unroll
    for (int r = 0; r < 8; ++r) {
      const v2f lo = a[r], hi = a[r + 8];
      a[r].x = cn34 ? hi.x : lo.x;  a[r].y = cn34 ? hi.y : lo.y;
      a[r + 8].x = cn34 ? lo.x : hi.x;  a[r + 8].y = cn34 ? lo.y : hi.y;
    }
    // CNOT(4,5),(5,6),(6,7): static register renames (free)
    swap_v(a[8], a[12]);  swap_v(a[9], a[13]);  swap_v(a[10], a[14]); swap_v(a[11], a[15]);
    swap_v(a[4], a[6]);   swap_v(a[5], a[7]);   swap_v(a[12], a[14]); swap_v(a[13], a[15]);
    swap_v(a[2], a[3]);   swap_v(a[6], a[7]);   swap_v(a[10], a[11]); swap_v(a[14], a[15]);
    // CNOT(7,0): ctrl r-bit1 (odd regs), tgt qubit0=xor8 -> unconditional DPP
#pragma unroll
    for (int r = 1; r < 16; r += 2) {
      a[r].x = shx<8>(a[r].x);
      a[r].y = shx<8>(a[r].y);
    }
  }

  // ---- Phase D: <Z_q> ----
  float p[16];
#pragma unroll
  for (int r = 0; r < 16; ++r) p[r] = __builtin_fmaf(a[r].x, a[r].x, a[r].y * a[r].y);
  float e0[8], d7 = 0.f;
#pragma unroll
  for (int k = 0; k < 8; ++k) { e0[k] = p[2*k] + p[2*k+1]; d7 += p[2*k] - p[2*k+1]; }
  float e1[4], d6 = 0.f;
#pragma unroll
  for (int k = 0; k < 4; ++k) { e1[k] = e0[2*k] + e0[2*k+1]; d6 += e0[2*k] - e0[2*k+1]; }
  float e2[2], d5 = 0.f;
#pragma unroll
  for (int k = 0; k < 2; ++k) { e2[k] = e1[2*k] + e1[2*k+1]; d5 += e1[2*k] - e1[2*k+1]; }
  float S  = e2[0] + e2[1];
  float d4 = e2[0] - e2[1];

  float t;
  t = shx<1>(S);  float d3 = S - t;  S += t;
  d4 += shx<1>(d4); d5 += shx<1>(d5); d6 += shx<1>(d6); d7 += shx<1>(d7);
  t = shx<2>(S);  float d2 = S - t;  S += t;
  d3 += shx<2>(d3); d4 += shx<2>(d4); d5 += shx<2>(d5); d6 += shx<2>(d6); d7 += shx<2>(d7);
  t = shx<4>(S);  float d1 = S - t;  S += t;
  d2 += shx<4>(d2); d3 += shx<4>(d3); d4 += shx<4>(d4); d5 += shx<4>(d5); d6 += shx<4>(d6); d7 += shx<4>(d7);
  t = shx<8>(S);  float d0 = S - t;
  d1 += shx<8>(d1); d2 += shx<8>(d2); d3 += shx<8>(d3); d4 += shx<8>(d4); d5 += shx<8>(d5); d6 += shx<8>(d6); d7 += shx<8>(d7);

  // mapping: stage xor8 -> qubit0, xor2 -> qubit1, xor4 -> qubit2, xor1 -> qubit3
  float z[8];
  z[0] = (u & 8) ? -d0 : d0;
  z[1] = (u & 2) ? -d2 : d2;
  z[2] = (u & 4) ? -d1 : d1;
  z[3] = (u & 1) ? -d3 : d3;
  z[4] = d4; z[5] = d5; z[6] = d6; z[7] = d7;

  // ---- Phase E: out = z @ post_w^T + post_b (packed) ----
  v2f zz[8];
#pragma unroll
  for (int q = 0; q < 8; ++q) { zz[q].x = z[q]; zz[q].y = z[q]; }
  float* orow = out + (size_t)smp * 512;
#pragma unroll
  for (int tt = 0; tt < 8; ++tt) {
    const int o = u * 4 + tt * 64;
    const float4 pbv = *(const float4*)(s_pb + o);
    v2f r0; r0.x = pbv.x; r0.y = pbv.y;
    v2f r1; r1.x = pbv.z; r1.y = pbv.w;
#pragma unroll
    for (int q = 0; q < 8; ++q) {
      const float4 wv = *(const float4*)(s_pwt + q * 512 + o);
      v2f w01; w01.x = wv.x; w01.y = wv.y;
      v2f w23; w23.x = wv.z; w23.y = wv.w;
      r0 = pk_fma(zz[q], w01, r0);
      r1 = pk_fma(zz[q], w23, r1);
    }
    float4 ov; ov.x = r0.x; ov.y = r0.y; ov.z = r1.x; ov.w = r1.y;
    *(float4*)(orow + o) = ov;
  }
}

extern "C" void kernel_launch(void* const* d_in, const int* in_sizes, int n_in,
                              void* d_out, int out_size, void* d_ws, size_t ws_size,
                              hipStream_t stream) {
  const float* x   = (const float*)d_in[0];
  const float* fcw = (const float*)d_in[1];
  const float* fcb = (const float*)d_in[2];
  const float* qp  = (const float*)d_in[3];
  const float* pw  = (const float*)d_in[4];
  const float* pb  = (const float*)d_in[5];
  float* out = (float*)d_out;

  // 32768 samples / (4 per wave * 8 waves per block) = 1024 blocks
  dim3 grid(1024), block(BLOCK);
  hipLaunchKernelGGL(qcnn_kernel, grid, block, 0, stream, x, fcw, fcb, qp, pw, pb, out);
}